// Round 1
// baseline (625.902 us; speedup 1.0000x reference)
//
#include <hip/hip_runtime.h>
#include <hip/hip_bf16.h>
#include <stdint.h>

#define VOCAB 50257
#define VPAD  50304   /* 393*128 */
#define DIM   640
#define SEQ   256
#define NBATCH 16
#define MROWS 4096    /* NBATCH*SEQ */

using bf16 = __hip_bfloat16;
typedef __attribute__((ext_vector_type(8))) short short8;
typedef __attribute__((ext_vector_type(4))) float f32x4;

__device__ __forceinline__ void gld_lds16(const void* g, void* l) {
  __builtin_amdgcn_global_load_lds(
      (const __attribute__((address_space(1))) void*)g,
      (__attribute__((address_space(3))) void*)l, 16, 0, 0);
}

// ---------------- embed: x = w_embed[idx] + w_pos  -> bf16 ----------------
__global__ void embed_kernel(const int* __restrict__ idx,
                             const float* __restrict__ we,
                             const float* __restrict__ wp,
                             bf16* __restrict__ xb) {
  int row = blockIdx.x;              // 0..4095  (b*SEQ + t)
  int t = row & (SEQ - 1);
  int tok = idx[row];
  const float* src = we + (long)tok * DIM;
  const float* pos = wp + (long)t * DIM;
  for (int d = threadIdx.x; d < DIM; d += blockDim.x)
    xb[(long)row * DIM + d] = __float2bfloat16(src[d] + pos[d]);
}

// ---------------- f32 -> bf16 convert with zero tail pad ----------------
__global__ void conv_kernel(const float* __restrict__ src, bf16* __restrict__ dst,
                            long n_src, long n_dst) {
  long i = (long)blockIdx.x * blockDim.x + threadIdx.x;
  long stride = (long)gridDim.x * blockDim.x;
  for (; i < n_dst; i += stride)
    dst[i] = __float2bfloat16(i < n_src ? src[i] : 0.f);
}

// ---------------- v (16*256,640) -> vT (16,640,256) ----------------
__global__ void transpose_v(const bf16* __restrict__ v, bf16* __restrict__ vt) {
  long i = (long)blockIdx.x * blockDim.x + threadIdx.x;
  if (i >= (long)NBATCH * DIM * SEQ) return;
  int t = (int)(i & (SEQ - 1));
  long be = i >> 8;
  int e = (int)(be % DIM);
  int b = (int)(be / DIM);
  vt[i] = v[((long)b * SEQ + t) * DIM + e];
}

// ---------------- causal softmax: scores f32 -> P bf16 ----------------
__global__ void softmax_kernel(const float* __restrict__ sc, bf16* __restrict__ p) {
  int wid = threadIdx.x >> 6, lane = threadIdx.x & 63;
  int row = blockIdx.x * 4 + wid;          // b*SEQ + t
  int t = row & (SEQ - 1);
  const float* srow = sc + (long)row * SEQ;
  const float rsc = 0.03952847075210474f;  // 1/sqrt(640)
  float v[4];
  float mx = -1e30f;
#pragma unroll
  for (int i = 0; i < 4; ++i) {
    int s = lane + 64 * i;
    v[i] = (s <= t) ? srow[s] * rsc : -1e30f;
    mx = fmaxf(mx, v[i]);
  }
#pragma unroll
  for (int off = 32; off; off >>= 1) mx = fmaxf(mx, __shfl_xor(mx, off, 64));
  float sum = 0.f;
#pragma unroll
  for (int i = 0; i < 4; ++i) {
    int s = lane + 64 * i;
    v[i] = (s <= t) ? __expf(v[i] - mx) : 0.f;
    sum += v[i];
  }
#pragma unroll
  for (int off = 32; off; off >>= 1) sum += __shfl_xor(sum, off, 64);
  float inv = 1.f / sum;
#pragma unroll
  for (int i = 0; i < 4; ++i)
    p[(long)row * SEQ + lane + 64 * i] = __float2bfloat16(v[i] * inv);
}

// ---------------- generic C = A * B^T  (m97-style 128x128 tile) ----------------
// A: (Mtiles*128, K) bf16 row-major, B: (Ntiles*128, K) bf16 row-major.
// C[m,n] = sum_k A[m,k]*B[n,k]  (+bias[n]).  Stores masked to col < Nstore.
template <typename OUT_T, bool BIAS>
__global__ __launch_bounds__(256, 2) void gemm_bt(
    const bf16* __restrict__ Ag, const bf16* __restrict__ Bg,
    OUT_T* __restrict__ Cg, const float* __restrict__ bias,
    int K, int ldc, int Nstore, long sA, long sB, long sC) {
  __shared__ bf16 As[128 * 32];
  __shared__ bf16 Bs[128 * 32];
  const int tid = threadIdx.x;
  const int wv = tid >> 6, lane = tid & 63;
  const int tm = blockIdx.x * 128, tn = blockIdx.y * 128;
  const int bz = blockIdx.z;
  const bf16* A = Ag + (long)bz * sA + (long)tm * K;
  const bf16* B = Bg + (long)bz * sB + (long)tn * K;

  f32x4 acc[4][4] = {};
  const int wr = (wv >> 1) * 64, wc = (wv & 1) * 64;
  const int lr = lane & 15, lk = (lane >> 4) * 8;
  const int srow0 = wv * 32;              // wave's staging rows
  const int g_r = lane >> 2, g_k = (lane & 3) * 8;

  for (int k0 = 0; k0 < K; k0 += 32) {
#pragma unroll
    for (int j = 0; j < 2; ++j) {
      int r = srow0 + j * 16;
      gld_lds16(A + (long)(r + g_r) * K + k0 + g_k, &As[r * 32]);
      gld_lds16(B + (long)(r + g_r) * K + k0 + g_k, &Bs[r * 32]);
    }
    __syncthreads();
    short8 a[4], b[4];
#pragma unroll
    for (int m = 0; m < 4; ++m)
      a[m] = *(const short8*)&As[(wr + m * 16 + lr) * 32 + lk];
#pragma unroll
    for (int n = 0; n < 4; ++n)
      b[n] = *(const short8*)&Bs[(wc + n * 16 + lr) * 32 + lk];
#pragma unroll
    for (int m = 0; m < 4; ++m)
#pragma unroll
      for (int n = 0; n < 4; ++n)
        acc[m][n] = __builtin_amdgcn_mfma_f32_16x16x32_bf16(a[m], b[n], acc[m][n], 0, 0, 0);
    __syncthreads();
  }

  OUT_T* C = Cg + (long)bz * sC;
  const int crow0 = tm + wr + (lane >> 4) * 4;
  const int ccol0 = tn + wc + (lane & 15);
#pragma unroll
  for (int m = 0; m < 4; ++m)
#pragma unroll
    for (int n = 0; n < 4; ++n) {
      int col = ccol0 + n * 16;
      if (col < Nstore) {
        float bv = BIAS ? bias[col] : 0.f;
#pragma unroll
        for (int j = 0; j < 4; ++j) {
          long row = crow0 + m * 16 + j;
          float val = acc[m][n][j] + bv;
          if constexpr (sizeof(OUT_T) == 2)
            C[row * ldc + col] = __float2bfloat16(val);
          else
            C[row * ldc + col] = val;
        }
      }
    }
}

extern "C" void kernel_launch(void* const* d_in, const int* in_sizes, int n_in,
                              void* d_out, int out_size, void* d_ws, size_t ws_size,
                              hipStream_t stream) {
  const int*   idx     = (const int*)d_in[0];
  const float* w_embed = (const float*)d_in[1];
  const float* w_pos   = (const float*)d_in[2];
  const float* wq      = (const float*)d_in[3];
  const float* wk      = (const float*)d_in[4];
  const float* wv      = (const float*)d_in[5];
  const float* w_out   = (const float*)d_in[6];
  const float* b_out   = (const float*)d_in[7];
  float* out = (float*)d_out;

  size_t off = 0;
  auto alloc = [&](size_t bytes) {
    void* p = (char*)d_ws + off;
    off += (bytes + 255) & ~(size_t)255;
    return p;
  };
  bf16* x_bf    = (bf16*)alloc((size_t)MROWS * DIM * 2);        // 4096x640
  bf16* wqkv_bf = (bf16*)alloc((size_t)3 * DIM * DIM * 2);      // 3x640x640
  bf16* wout_bf = (bf16*)alloc((size_t)VPAD * DIM * 2);         // 50304x640
  bf16* qkv     = (bf16*)alloc((size_t)3 * MROWS * DIM * 2);    // q,k,v each 4096x640
  bf16* vT      = (bf16*)alloc((size_t)NBATCH * DIM * SEQ * 2); // 16x640x256
  float* scores = (float*)alloc((size_t)NBATCH * SEQ * SEQ * 4);// 16x256x256
  bf16* P       = (bf16*)alloc((size_t)NBATCH * SEQ * SEQ * 2);
  bf16* attn    = (bf16*)alloc((size_t)MROWS * DIM * 2);

  const long QKV_S = (long)MROWS * DIM;   // 2621440 elems per q/k/v
  const long W_S   = (long)DIM * DIM;     // 409600

  // 1. embed
  embed_kernel<<<MROWS, 256, 0, stream>>>(idx, w_embed, w_pos, x_bf);

  // 2. weight converts (bf16; w_out zero-padded to VPAD rows)
  conv_kernel<<<512, 256, 0, stream>>>(wq, wqkv_bf,           W_S, W_S);
  conv_kernel<<<512, 256, 0, stream>>>(wk, wqkv_bf + W_S,     W_S, W_S);
  conv_kernel<<<512, 256, 0, stream>>>(wv, wqkv_bf + 2 * W_S, W_S, W_S);
  conv_kernel<<<4096, 256, 0, stream>>>(w_out, wout_bf, (long)VOCAB * DIM, (long)VPAD * DIM);

  // 3. q,k,v = x @ {wq,wk,wv}^T   (grid.z selects weight)
  gemm_bt<bf16, false><<<dim3(MROWS / 128, DIM / 128, 3), 256, 0, stream>>>(
      x_bf, wqkv_bf, qkv, nullptr, DIM, DIM, DIM, 0, W_S, QKV_S);

  // 4. vT per batch
  {
    long n = (long)NBATCH * DIM * SEQ;
    transpose_v<<<(int)((n + 255) / 256), 256, 0, stream>>>(qkv + 2 * QKV_S, vT);
  }

  // 5. scores[b] = q[b] @ k[b]^T   (M=N=256, K=640)
  gemm_bt<float, false><<<dim3(SEQ / 128, SEQ / 128, NBATCH), 256, 0, stream>>>(
      qkv, qkv + QKV_S, scores, nullptr, DIM, SEQ, SEQ,
      (long)SEQ * DIM, (long)SEQ * DIM, (long)SEQ * SEQ);

  // 6. causal softmax -> P bf16
  softmax_kernel<<<MROWS / 4, 256, 0, stream>>>(scores, P);

  // 7. attn[b] = P[b] @ vT[b]^T   (M=256, N=640, K=256)
  gemm_bt<bf16, false><<<dim3(SEQ / 128, DIM / 128, NBATCH), 256, 0, stream>>>(
      P, vT, attn, nullptr, SEQ, DIM, DIM,
      (long)SEQ * SEQ, (long)DIM * SEQ, (long)SEQ * DIM);

  // 8. logits = attn @ w_out^T + b_out   (M=4096, N=50304->50257, K=640)
  gemm_bt<float, true><<<dim3(MROWS / 128, VPAD / 128, 1), 256, 0, stream>>>(
      attn, wout_bf, out, b_out, DIM, VOCAB, VOCAB, 0, 0, 0);
}